// Round 5
// baseline (151.775 us; speedup 1.0000x reference)
//
#include <hip/hip_runtime.h>
#include <math.h>

#define NPTS   2048      // N
#define LFEAT  56        // C*L
#define HFEAT  128       // H
#define HALFW  8
#define NEIGH  17

// ---------------------------------------------------------------------------
// Kernel A: fused conv(dot over L) + BN + LeakyReLU for BOTH sources.
// Row space: rows [0, R) = input, rows [R, 2R) = state_memory, R = B*N.
// f_all[row*128 + h]
// ---------------------------------------------------------------------------
__global__ __launch_bounds__(256) void feat_kernel(
    const float* __restrict__ x_in, const float* __restrict__ x_mem,
    const float* __restrict__ conv_w, const float* __restrict__ conv_b,
    const float* __restrict__ gamma,  const float* __restrict__ beta,
    const float* __restrict__ bmean,  const float* __restrict__ bvar,
    float* __restrict__ f_all, int R)
{
    __shared__ float ws[HFEAT][LFEAT + 1];  // +1 pad: stride 57 (odd) -> conflict-free
    __shared__ float xs[8][LFEAT];
    __shared__ float sc[HFEAT], sh[HFEAT];

    const int tid = threadIdx.x;

    // stage conv_w (128x56 = 7168 floats) into padded LDS
    for (int i = tid; i < HFEAT * LFEAT; i += 256) {
        int h = i / LFEAT;
        int l = i - h * LFEAT;
        ws[h][l] = conv_w[i];
    }
    // fold BN into scale/shift:  f = dot*sc + sh
    if (tid < HFEAT) {
        float s = gamma[tid] / sqrtf(bvar[tid] + 1e-5f);
        sc[tid] = s;
        sh[tid] = (conv_b[tid] - bmean[tid]) * s + beta[tid];
    }

    // this block's 8 rows (all from the same source: R is a multiple of 8)
    const int base = blockIdx.x * 8;
    const float* src;
    int srow;
    if (base < R) { src = x_in;  srow = base; }
    else          { src = x_mem; srow = base - R; }

    for (int i = tid; i < 8 * LFEAT; i += 256) {
        xs[i / LFEAT][i % LFEAT] = src[srow * LFEAT + i];
    }
    __syncthreads();

    const int h    = tid & (HFEAT - 1);
    const int half = tid >> 7;           // 0 or 1
    #pragma unroll
    for (int j = 0; j < 4; ++j) {
        const int rr = half * 4 + j;
        float acc = 0.0f;
        #pragma unroll
        for (int l = 0; l < LFEAT; ++l) {
            acc = fmaf(xs[rr][l], ws[h][l], acc);
        }
        float f = acc * sc[h] + sh[h];
        f = (f >= 0.0f) ? f : 0.1f * f;          // LeakyReLU(0.1)
        f_all[(base + rr) * HFEAT + h] = f;
    }
}

// ---------------------------------------------------------------------------
// Kernel B: banded attention (17 neighbors, clamp->dedupe == skip-OOB) + PV
// against raw state_memory + blend with input. One wave per row.
// ---------------------------------------------------------------------------
__global__ __launch_bounds__(256) void attn_kernel(
    const float* __restrict__ f_all,
    const float* __restrict__ x_in, const float* __restrict__ x_mem,
    float* __restrict__ out, int R)
{
    const int wave = threadIdx.x >> 6;
    const int lane = threadIdx.x & 63;
    const int row  = blockIdx.x * 4 + wave;
    if (row >= R) return;

    const int n = row & (NPTS - 1);      // position within the batch (N=2048 pow2)

    // f_in fragment: lane holds elements 2*lane, 2*lane+1
    const float2 fi = ((const float2*)(f_all + (long)row * HFEAT))[lane];

    // 17 neighbor similarities (wave-uniform validity branch)
    float s[NEIGH];
    #pragma unroll
    for (int w = 0; w < NEIGH; ++w) {
        const int m = n + w - HALFW;
        float p = -1e30f;
        if (m >= 0 && m < NPTS) {
            const float2 fm =
                ((const float2*)(f_all + (long)(R + row + w - HALFW) * HFEAT))[lane];
            p = fi.x * fm.x + fi.y * fm.y;
            #pragma unroll
            for (int off = 32; off >= 1; off >>= 1)
                p += __shfl_xor(p, off);
        }
        s[w] = p;
    }

    // softmax over valid entries (invalid: exp(-1e30 - mx) -> 0)
    float mx = s[0];
    #pragma unroll
    for (int w = 1; w < NEIGH; ++w) mx = fmaxf(mx, s[w]);
    float sum = 0.0f;
    #pragma unroll
    for (int w = 0; w < NEIGH; ++w) { s[w] = expf(s[w] - mx); sum += s[w]; }
    const float inv = 1.0f / sum;

    // PV against raw state_memory + blend (RATE = 0.5)
    if (lane < LFEAT) {
        float acc = 0.0f;
        #pragma unroll
        for (int w = 0; w < NEIGH; ++w) {
            const int m = n + w - HALFW;
            if (m >= 0 && m < NPTS)
                acc = fmaf(s[w], x_mem[(long)(row + w - HALFW) * LFEAT + lane], acc);
        }
        out[(long)row * LFEAT + lane] =
            0.5f * x_in[(long)row * LFEAT + lane] + 0.5f * acc * inv;
    }
}

// ---------------------------------------------------------------------------
extern "C" void kernel_launch(void* const* d_in, const int* in_sizes, int n_in,
                              void* d_out, int out_size, void* d_ws, size_t ws_size,
                              hipStream_t stream)
{
    const float* input  = (const float*)d_in[0];
    const float* smem   = (const float*)d_in[1];
    const float* conv_w = (const float*)d_in[2];
    const float* conv_b = (const float*)d_in[3];
    const float* gamma  = (const float*)d_in[4];
    const float* beta   = (const float*)d_in[5];
    const float* bmean  = (const float*)d_in[6];
    const float* bvar   = (const float*)d_in[7];
    float* out = (float*)d_out;

    const int R = in_sizes[0] / LFEAT;   // B*N = 16384
    float* f_all = (float*)d_ws;         // 2*R*128 floats = 16 MB

    const int blocksA = (2 * R) / 8;     // 8 rows per block
    feat_kernel<<<blocksA, 256, 0, stream>>>(input, smem, conv_w, conv_b,
                                             gamma, beta, bmean, bvar, f_all, R);

    const int blocksB = (R + 3) / 4;     // 4 waves per block, 1 row per wave
    attn_kernel<<<blocksB, 256, 0, stream>>>(f_all, input, smem, out, R);
}

// Round 8
// 138.158 us; speedup vs baseline: 1.0986x; 1.0986x over previous
//
#include <hip/hip_runtime.h>
#include <math.h>

#define NPTS   2048      // N
#define LFEAT  56        // C*L
#define HFEAT  128       // H
#define HALFW  8
#define NEIGH  17
#define ROWSB  32        // rows per feat block

// ---------------------------------------------------------------------------
// Kernel A (rewritten): conv(dot over L) + BN + LeakyReLU for BOTH sources.
// Thread owns one h: conv_w row in 56 VGPRs. The x-row address is wave-uniform
// so its loads scalarize to s_load_* (SGPR operand feeds v_fmac directly).
// Row space: rows [0, R) = input, rows [R, 2R) = state_memory, R = B*N.
// ---------------------------------------------------------------------------
__global__ __launch_bounds__(128) void feat_kernel(
    const float* __restrict__ x_in, const float* __restrict__ x_mem,
    const float* __restrict__ conv_w, const float* __restrict__ conv_b,
    const float* __restrict__ gamma,  const float* __restrict__ beta,
    const float* __restrict__ bmean,  const float* __restrict__ bvar,
    float* __restrict__ f_all, int R)
{
    const int h = threadIdx.x;           // 0..127

    // conv_w row -> 14 float4 = 56 VGPRs (statically indexed, fully unrolled)
    float4 w4[14];
    #pragma unroll
    for (int q = 0; q < 14; ++q)
        w4[q] = ((const float4*)(conv_w + h * LFEAT))[q];

    // fold BN: f = dot*sc + sh
    const float sc = gamma[h] / sqrtf(bvar[h] + 1e-5f);
    const float sh = (conv_b[h] - bmean[h]) * sc + beta[h];

    const int base = blockIdx.x * ROWSB;           // uniform
    const float* src;
    int srow;
    if (base < R) { src = x_in;  srow = base; }
    else          { src = x_mem; srow = base - R; }

    #pragma unroll 4
    for (int r = 0; r < ROWSB; ++r) {
        // wave-uniform row pointer -> scalar loads
        const float4* xrow = (const float4*)(src + (long)(srow + r) * LFEAT);
        float acc = 0.0f;
        #pragma unroll
        for (int q = 0; q < 14; ++q) {
            const float4 x = xrow[q];
            acc = fmaf(x.x, w4[q].x, acc);
            acc = fmaf(x.y, w4[q].y, acc);
            acc = fmaf(x.z, w4[q].z, acc);
            acc = fmaf(x.w, w4[q].w, acc);
        }
        float f = acc * sc + sh;
        f = (f >= 0.0f) ? f : 0.1f * f;            // LeakyReLU(0.1)
        f_all[(long)(base + r) * HFEAT + h] = f;   // coalesced (lanes = consecutive h)
    }
}

// ---------------------------------------------------------------------------
// Kernel B (unchanged): banded attention (17 neighbors, clamp->dedupe ==
// skip-OOB) + PV against raw state_memory + blend with input. One wave/row.
// ---------------------------------------------------------------------------
__global__ __launch_bounds__(256) void attn_kernel(
    const float* __restrict__ f_all,
    const float* __restrict__ x_in, const float* __restrict__ x_mem,
    float* __restrict__ out, int R)
{
    const int wave = threadIdx.x >> 6;
    const int lane = threadIdx.x & 63;
    const int row  = blockIdx.x * 4 + wave;
    if (row >= R) return;

    const int n = row & (NPTS - 1);      // position within the batch (N=2048 pow2)

    // f_in fragment: lane holds elements 2*lane, 2*lane+1
    const float2 fi = ((const float2*)(f_all + (long)row * HFEAT))[lane];

    // 17 neighbor similarities (wave-uniform validity branch)
    float s[NEIGH];
    #pragma unroll
    for (int w = 0; w < NEIGH; ++w) {
        const int m = n + w - HALFW;
        float p = -1e30f;
        if (m >= 0 && m < NPTS) {
            const float2 fm =
                ((const float2*)(f_all + (long)(R + row + w - HALFW) * HFEAT))[lane];
            p = fi.x * fm.x + fi.y * fm.y;
            #pragma unroll
            for (int off = 32; off >= 1; off >>= 1)
                p += __shfl_xor(p, off);
        }
        s[w] = p;
    }

    // softmax over valid entries (invalid: exp(-1e30 - mx) -> 0)
    float mx = s[0];
    #pragma unroll
    for (int w = 1; w < NEIGH; ++w) mx = fmaxf(mx, s[w]);
    float sum = 0.0f;
    #pragma unroll
    for (int w = 0; w < NEIGH; ++w) { s[w] = expf(s[w] - mx); sum += s[w]; }
    const float inv = 1.0f / sum;

    // PV against raw state_memory + blend (RATE = 0.5)
    if (lane < LFEAT) {
        float acc = 0.0f;
        #pragma unroll
        for (int w = 0; w < NEIGH; ++w) {
            const int m = n + w - HALFW;
            if (m >= 0 && m < NPTS)
                acc = fmaf(s[w], x_mem[(long)(row + w - HALFW) * LFEAT + lane], acc);
        }
        out[(long)row * LFEAT + lane] =
            0.5f * x_in[(long)row * LFEAT + lane] + 0.5f * acc * inv;
    }
}

// ---------------------------------------------------------------------------
extern "C" void kernel_launch(void* const* d_in, const int* in_sizes, int n_in,
                              void* d_out, int out_size, void* d_ws, size_t ws_size,
                              hipStream_t stream)
{
    const float* input  = (const float*)d_in[0];
    const float* smem   = (const float*)d_in[1];
    const float* conv_w = (const float*)d_in[2];
    const float* conv_b = (const float*)d_in[3];
    const float* gamma  = (const float*)d_in[4];
    const float* beta   = (const float*)d_in[5];
    const float* bmean  = (const float*)d_in[6];
    const float* bvar   = (const float*)d_in[7];
    float* out = (float*)d_out;

    const int R = in_sizes[0] / LFEAT;   // B*N = 16384
    float* f_all = (float*)d_ws;         // 2*R*128 floats = 16 MB

    const int blocksA = (2 * R) / ROWSB;   // 1024 blocks, 128 threads each
    feat_kernel<<<blocksA, 128, 0, stream>>>(input, smem, conv_w, conv_b,
                                             gamma, beta, bmean, bvar, f_all, R);

    const int blocksB = (R + 3) / 4;     // 4 waves per block, 1 row per wave
    attn_kernel<<<blocksB, 256, 0, stream>>>(f_all, input, smem, out, R);
}